// Round 1
// baseline (4649.207 us; speedup 1.0000x reference)
//
#include <hip/hip_runtime.h>
#include <cstdint>
#include <cstddef>

#define T_STEPS 32
#define BN_DIM  2048     // B*N
#define C_DIM   512
#define H_DIM   1024
#define O_DIM   512
#define TBN_DIM 65536    // T_STEPS*BN_DIM

__device__ __forceinline__ float bf2f(unsigned short u){
    return __uint_as_float(((unsigned int)u) << 16);
}

// C = A @ B^T, A: [M,K] (fp32 or bf16), B: [N,K] fp32.
// MODE 0: fc1  -> Cout = acc + bias
// MODE 1: rec  -> PLIF update epilogue (reads curr_t, v; writes v, spikes)
// MODE 2: fc2  -> Cout = acc + bias, plus per-block channel sum/sumsq partials
template<int MODE, int BM, int BN, int BK, int TM, int TN, bool ABF16>
__global__ __launch_bounds__(256)
void gemm_fused(const void* __restrict__ Ap,
                const float* __restrict__ Bp,
                int K, int ldc,
                const float* __restrict__ bias,
                const float* __restrict__ curr_t,
                float* __restrict__ vstate,
                unsigned short* __restrict__ spk_out,
                const float* __restrict__ wlif,
                float* __restrict__ Cout,
                float* __restrict__ partials)
{
    constexpr int BMP = BM + 4;
    constexpr int BNP = BN + 4;
    __shared__ float smem[BK*BMP + BK*BNP];
    float* As = smem;
    float* Bs = smem + BK*BMP;

    const int tid = threadIdx.x;
    constexpr int TXN = BN / TN;
    const int tx = tid % TXN;
    const int ty = tid / TXN;
    const int bm0 = blockIdx.y * BM;
    const int bn0 = blockIdx.x * BN;

    float acc[TM][TN];
#pragma unroll
    for (int i = 0; i < TM; ++i)
#pragma unroll
        for (int j = 0; j < TN; ++j) acc[i][j] = 0.f;

    for (int kt = 0; kt < K; kt += BK) {
        // ---- stage A tile -> As[k][m] ----
        if constexpr (ABF16) {
            const unsigned short* A = (const unsigned short*)Ap;
            constexpr int PT = (BM*BK/4)/256;
#pragma unroll
            for (int it = 0; it < PT; ++it) {
                int e   = it*256 + tid;
                int row = e / (BK/4);
                int c4  = e % (BK/4);
                const unsigned short* src = A + (size_t)(bm0+row)*K + kt + c4*4;
                ushort4 uv = *(const ushort4*)src;
                As[(c4*4+0)*BMP + row] = bf2f(uv.x);
                As[(c4*4+1)*BMP + row] = bf2f(uv.y);
                As[(c4*4+2)*BMP + row] = bf2f(uv.z);
                As[(c4*4+3)*BMP + row] = bf2f(uv.w);
            }
        } else {
            const float* A = (const float*)Ap;
            constexpr int PT = (BM*BK/4)/256;
#pragma unroll
            for (int it = 0; it < PT; ++it) {
                int e   = it*256 + tid;
                int row = e / (BK/4);
                int c4  = e % (BK/4);
                float4 fv = *(const float4*)(A + (size_t)(bm0+row)*K + kt + c4*4);
                As[(c4*4+0)*BMP + row] = fv.x;
                As[(c4*4+1)*BMP + row] = fv.y;
                As[(c4*4+2)*BMP + row] = fv.z;
                As[(c4*4+3)*BMP + row] = fv.w;
            }
        }
        // ---- stage B tile -> Bs[k][n] ----
        {
            constexpr int PT = (BN*BK/4)/256;
#pragma unroll
            for (int it = 0; it < PT; ++it) {
                int e   = it*256 + tid;
                int row = e / (BK/4);
                int c4  = e % (BK/4);
                float4 fv = *(const float4*)(Bp + (size_t)(bn0+row)*K + kt + c4*4);
                Bs[(c4*4+0)*BNP + row] = fv.x;
                Bs[(c4*4+1)*BNP + row] = fv.y;
                Bs[(c4*4+2)*BNP + row] = fv.z;
                Bs[(c4*4+3)*BNP + row] = fv.w;
            }
        }
        __syncthreads();
#pragma unroll
        for (int k = 0; k < BK; ++k) {
            float a[TM], b[TN];
#pragma unroll
            for (int i = 0; i < TM/4; ++i) {
                float4 t4 = *(const float4*)&As[k*BMP + ty*TM + i*4];
                a[i*4+0] = t4.x; a[i*4+1] = t4.y; a[i*4+2] = t4.z; a[i*4+3] = t4.w;
            }
#pragma unroll
            for (int j = 0; j < TN/4; ++j) {
                float4 t4 = *(const float4*)&Bs[k*BNP + tx*TN + j*4];
                b[j*4+0] = t4.x; b[j*4+1] = t4.y; b[j*4+2] = t4.z; b[j*4+3] = t4.w;
            }
#pragma unroll
            for (int i = 0; i < TM; ++i)
#pragma unroll
                for (int j = 0; j < TN; ++j)
                    acc[i][j] = fmaf(a[i], b[j], acc[i][j]);
        }
        __syncthreads();
    }

    if constexpr (MODE == 0) {
#pragma unroll
        for (int i = 0; i < TM; ++i) {
            int m = bm0 + ty*TM + i;
#pragma unroll
            for (int j = 0; j < TN/4; ++j) {
                int n = bn0 + tx*TN + j*4;
                float4 bv = *(const float4*)&bias[n];
                float4 o;
                o.x = acc[i][j*4+0] + bv.x;
                o.y = acc[i][j*4+1] + bv.y;
                o.z = acc[i][j*4+2] + bv.z;
                o.w = acc[i][j*4+3] + bv.w;
                *(float4*)&Cout[(size_t)m*ldc + n] = o;
            }
        }
    } else if constexpr (MODE == 1) {
        float decay = 1.f / (1.f + expf(-wlif[0]));
#pragma unroll
        for (int i = 0; i < TM; ++i) {
            int m = bm0 + ty*TM + i;
#pragma unroll
            for (int j = 0; j < TN; ++j) {
                int n = bn0 + tx*TN + j;
                size_t idx = (size_t)m*H_DIM + n;
                float inp = acc[i][j] + bias[n] + curr_t[idx];
                float vv  = vstate[idx];
                vv = vv + (inp - vv) * decay;
                bool s = (vv - 1.0f) >= 0.0f;          // Heaviside(v - V_TH)
                vstate[idx]  = s ? 0.0f : vv;          // hard reset
                spk_out[idx] = s ? (unsigned short)0x3F80 : (unsigned short)0;
            }
        }
    } else { // MODE == 2
        float colsum[TN], colsq[TN];
#pragma unroll
        for (int j = 0; j < TN; ++j) { colsum[j] = 0.f; colsq[j] = 0.f; }
#pragma unroll
        for (int i = 0; i < TM; ++i) {
            int m = bm0 + ty*TM + i;
            float rowv[TN];
#pragma unroll
            for (int j = 0; j < TN; ++j) {
                int n = bn0 + tx*TN + j;
                float o = acc[i][j] + bias[n];
                rowv[j] = o;
                colsum[j] += o;
                colsq[j]  += o*o;
            }
#pragma unroll
            for (int j = 0; j < TN/4; ++j) {
                int n = bn0 + tx*TN + j*4;
                float4 o4;
                o4.x = rowv[j*4+0]; o4.y = rowv[j*4+1];
                o4.z = rowv[j*4+2]; o4.w = rowv[j*4+3];
                *(float4*)&Cout[(size_t)m*ldc + n] = o4;
            }
        }
        __syncthreads();           // all done with As/Bs; reuse smem for reduce
        float* redS = smem;
        float* redQ = smem + (BM/TM)*BN;
#pragma unroll
        for (int j = 0; j < TN; ++j) {
            redS[ty*BN + tx*TN + j] = colsum[j];
            redQ[ty*BN + tx*TN + j] = colsq[j];
        }
        __syncthreads();
        if (tid < BN) {
            float s = 0.f, q = 0.f;
            for (int r = 0; r < BM/TM; ++r) { s += redS[r*BN + tid]; q += redQ[r*BN + tid]; }
            partials[((size_t)blockIdx.y*2 + 0)*O_DIM + bn0 + tid] = s;
            partials[((size_t)blockIdx.y*2 + 1)*O_DIM + bn0 + tid] = q;
        }
    }
}

__global__ void bn_finalize(const float* __restrict__ partials,
                            const float* __restrict__ gamma,
                            const float* __restrict__ beta,
                            float* __restrict__ scsh, int nmblk)
{
    int o = threadIdx.x;   // 512 threads
    float s = 0.f, q = 0.f;
    for (int mb = 0; mb < nmblk; ++mb) {
        s += partials[((size_t)mb*2 + 0)*O_DIM + o];
        q += partials[((size_t)mb*2 + 1)*O_DIM + o];
    }
    const float invn = 1.f / (float)TBN_DIM;
    float mean = s * invn;
    float var  = q * invn - mean*mean;
    float sc   = gamma[o] * rsqrtf(var + 1e-5f);
    scsh[o]        = sc;
    scsh[O_DIM+o]  = beta[o] - mean*sc;
}

__global__ void bn_apply(float* __restrict__ out, const float* __restrict__ scsh)
{
    const size_t total4 = (size_t)TBN_DIM * O_DIM / 4;   // 8,388,608 float4
    const float4* sc4 = (const float4*)scsh;
    const float4* sh4 = (const float4*)(scsh + O_DIM);
    size_t stride = (size_t)gridDim.x * blockDim.x;
    for (size_t idx = (size_t)blockIdx.x*blockDim.x + threadIdx.x; idx < total4; idx += stride) {
        float4 v = ((float4*)out)[idx];
        int c4 = (int)(idx & (O_DIM/4 - 1));
        float4 sc = sc4[c4], sh = sh4[c4];
        v.x = v.x*sc.x + sh.x;
        v.y = v.y*sc.y + sh.y;
        v.z = v.z*sc.z + sh.z;
        v.w = v.w*sc.w + sh.w;
        ((float4*)out)[idx] = v;
    }
}

extern "C" void kernel_launch(void* const* d_in, const int* in_sizes, int n_in,
                              void* d_out, int out_size, void* d_ws, size_t ws_size,
                              hipStream_t stream) {
    const float* x     = (const float*)d_in[0];   // [T,B,N,C] fp32
    const float* W1    = (const float*)d_in[1];   // [H,C]
    const float* b1    = (const float*)d_in[2];   // [H]
    const float* Wrec  = (const float*)d_in[3];   // [H,H]
    const float* brec  = (const float*)d_in[4];   // [H]
    const float* wlif  = (const float*)d_in[5];   // scalar
    const float* W2    = (const float*)d_in[6];   // [O,H]
    const float* b2    = (const float*)d_in[7];   // [O]
    const float* gamma = (const float*)d_in[8];   // [O]
    const float* beta  = (const float*)d_in[9];   // [O]
    float* out = (float*)d_out;                   // [T,B,N,O] fp32

    // workspace carve (total ~417.3 MB)
    const size_t CURR_BYTES = (size_t)TBN_DIM * H_DIM * 4;               // 268,435,456
    const size_t SPK_BYTES  = (size_t)(T_STEPS+1) * BN_DIM * H_DIM * 2;  // 138,412,032
    const size_t V_BYTES    = (size_t)BN_DIM * H_DIM * 4;                //   8,388,608
    const size_t PART_BYTES = (size_t)512 * 2 * O_DIM * 4;               //   2,097,152
    char* w = (char*)d_ws;
    float*          curr     = (float*)w;
    unsigned short* spk      = (unsigned short*)(w + CURR_BYTES);
    float*          vstate   = (float*)(w + CURR_BYTES + SPK_BYTES);
    float*          partials = (float*)(w + CURR_BYTES + SPK_BYTES + V_BYTES);
    float*          scsh     = (float*)(w + CURR_BYTES + SPK_BYTES + V_BYTES + PART_BYTES);

    // zero v state and initial spike slot every call (deterministic)
    hipMemsetAsync(vstate, 0, V_BYTES, stream);
    hipMemsetAsync(spk, 0, (size_t)BN_DIM * H_DIM * 2, stream);

    // fc1: curr = x @ W1^T + b1    [65536,512]x[1024,512] -> [65536,1024]
    gemm_fused<0,128,128,16,8,8,false>
        <<<dim3(H_DIM/128, TBN_DIM/128), 256, 0, stream>>>(
            x, W1, C_DIM, H_DIM, b1,
            nullptr, nullptr, nullptr, nullptr, curr, nullptr);

    // recurrent scan: 32 fused steps
    for (int t = 0; t < T_STEPS; ++t) {
        const unsigned short* spk_prev = spk + (size_t)t * BN_DIM * H_DIM;
        unsigned short* spk_next = spk + (size_t)(t+1) * BN_DIM * H_DIM;
        const float* curr_t = curr + (size_t)t * BN_DIM * H_DIM;
        gemm_fused<1,64,128,16,4,8,true>
            <<<dim3(H_DIM/128, BN_DIM/64), 256, 0, stream>>>(
                spk_prev, Wrec, H_DIM, H_DIM, brec,
                curr_t, vstate, spk_next, wlif, nullptr, nullptr);
    }

    // fc2: out_preBN = spikes @ W2^T + b2 -> d_out, + channel partial stats
    gemm_fused<2,128,128,16,8,8,true>
        <<<dim3(O_DIM/128, TBN_DIM/128), 256, 0, stream>>>(
            spk + (size_t)BN_DIM*H_DIM, W2, H_DIM, O_DIM, b2,
            nullptr, nullptr, nullptr, nullptr, out, partials);

    // BN stats finalize + apply
    bn_finalize<<<1, O_DIM, 0, stream>>>(partials, gamma, beta, scsh, TBN_DIM/128);
    bn_apply<<<2048, 256, 0, stream>>>(out, scsh);
}

// Round 5
// 4234.766 us; speedup vs baseline: 1.0979x; 1.0979x over previous
//
#include <hip/hip_runtime.h>
#include <cstdint>
#include <cstddef>

#define T_STEPS 32
#define BNROWS  2048     // B*N
#define C_DIM   512
#define H_DIM   1024
#define O_DIM   512
#define TBN_DIM 65536    // T_STEPS*BNROWS

typedef __attribute__((ext_vector_type(8))) short bf16x8;
typedef __attribute__((ext_vector_type(4))) float f32x4;

__device__ __forceinline__ float bf2f(unsigned short u){
    return __uint_as_float(((unsigned int)u) << 16);
}

// Exact 3-way truncation split: x == h + m + l exactly.
__device__ __forceinline__ void split3(float x, unsigned short& h,
                                       unsigned short& m, unsigned short& l){
    unsigned u = __float_as_uint(x);
    h = (unsigned short)(u >> 16);
    float r1 = x - __uint_as_float(u & 0xFFFF0000u);
    unsigned u1 = __float_as_uint(r1);
    m = (unsigned short)(u1 >> 16);
    float r2 = r1 - __uint_as_float(u1 & 0xFFFF0000u);
    l = (unsigned short)(__float_as_uint(r2) >> 16);
}

__global__ void split3_w(const float* __restrict__ src,
                         unsigned short* __restrict__ hi,
                         unsigned short* __restrict__ mi,
                         unsigned short* __restrict__ lo, int n4)
{
    int i = blockIdx.x * blockDim.x + threadIdx.x;
    int stride = gridDim.x * blockDim.x;
    for (; i < n4; i += stride) {
        float4 v = ((const float4*)src)[i];
        ushort4 h, m, l;
        split3(v.x, h.x, m.x, l.x); split3(v.y, h.y, m.y, l.y);
        split3(v.z, h.z, m.z, l.z); split3(v.w, h.w, m.w, l.w);
        ((ushort4*)hi)[i] = h;
        ((ushort4*)mi)[i] = m;
        ((ushort4*)lo)[i] = l;
    }
}

// 8-byte-granular LDS helpers for the MFMA kernel (LP=40 ushort rows = 80 B)
__device__ __forceinline__ void st8x2(unsigned short* p, int4 v){
    ((int2*)p)[0] = make_int2(v.x, v.y);
    ((int2*)p)[1] = make_int2(v.z, v.w);
}
__device__ __forceinline__ bf16x8 ld_frag(const unsigned short* p){
    union { bf16x8 v; ushort4 u[2]; } t;
    t.u[0] = *(const ushort4*)(p);
    t.u[1] = *(const ushort4*)(p + 4);
    return t.v;
}

// t=0 PLIF step (prev spikes all zero). Bit-exact to round-1's GEMM-of-zeros:
// acc=+0.0 exactly; inp=(0+bias)+curr = bias+curr; v = 0+(inp-0)*0.5 = inp*0.5.
__global__ void step0_kernel(const float* __restrict__ curr0,
                             const float* __restrict__ brec,
                             const float* __restrict__ wlif,
                             float* __restrict__ vstate,
                             unsigned short* __restrict__ spk0)
{
    const float decay = 1.f / (1.f + expf(-wlif[0]));
    int i = blockIdx.x * blockDim.x + threadIdx.x;
    int stride = gridDim.x * blockDim.x;
    const int n4 = BNROWS * H_DIM / 4;
    for (; i < n4; i += stride) {
        float4 c = ((const float4*)curr0)[i];
        int col4 = (i * 4) & (H_DIM - 1);
        float4 b = *(const float4*)&brec[col4];
        float v0 = __fmul_rn(__fadd_rn(b.x, c.x), decay);
        float v1 = __fmul_rn(__fadd_rn(b.y, c.y), decay);
        float v2 = __fmul_rn(__fadd_rn(b.z, c.z), decay);
        float v3 = __fmul_rn(__fadd_rn(b.w, c.w), decay);
        bool s0 = (v0 - 1.0f) >= 0.0f, s1 = (v1 - 1.0f) >= 0.0f;
        bool s2 = (v2 - 1.0f) >= 0.0f, s3 = (v3 - 1.0f) >= 0.0f;
        float4 vo; vo.x = s0 ? 0.f : v0; vo.y = s1 ? 0.f : v1;
        vo.z = s2 ? 0.f : v2; vo.w = s3 ? 0.f : v3;
        ushort4 sp;
        sp.x = s0 ? 0x3F80 : 0; sp.y = s1 ? 0x3F80 : 0;
        sp.z = s2 ? 0x3F80 : 0; sp.w = s3 ? 0x3F80 : 0;
        ((float4*)vstate)[i] = vo;
        ((ushort4*)spk0)[i]  = sp;
    }
}

// ======== round-1 VERBATIM fp32 VALU GEMM (the proven spike-critical path) ====
// C = A @ B^T, A: [M,K] (fp32 or bf16), B: [N,K] fp32.
// MODE 0: fc1  -> Cout = acc + bias
// MODE 1: rec  -> PLIF update epilogue (reads curr_t, v; writes v, spikes)
template<int MODE, int BM, int BN, int BK, int TM, int TN, bool ABF16>
__global__ __launch_bounds__(256)
void gemm_fused(const void* __restrict__ Ap,
                const float* __restrict__ Bp,
                int K, int ldc,
                const float* __restrict__ bias,
                const float* __restrict__ curr_t,
                float* __restrict__ vstate,
                unsigned short* __restrict__ spk_out,
                const float* __restrict__ wlif,
                float* __restrict__ Cout)
{
    constexpr int BMP = BM + 4;
    constexpr int BNP = BN + 4;
    __shared__ float smem[BK*BMP + BK*BNP];
    float* As = smem;
    float* Bs = smem + BK*BMP;

    const int tid = threadIdx.x;
    constexpr int TXN = BN / TN;
    const int tx = tid % TXN;
    const int ty = tid / TXN;
    const int bm0 = blockIdx.y * BM;
    const int bn0 = blockIdx.x * BN;

    float acc[TM][TN];
#pragma unroll
    for (int i = 0; i < TM; ++i)
#pragma unroll
        for (int j = 0; j < TN; ++j) acc[i][j] = 0.f;

    for (int kt = 0; kt < K; kt += BK) {
        if constexpr (ABF16) {
            const unsigned short* A = (const unsigned short*)Ap;
            constexpr int PT = (BM*BK/4)/256;
#pragma unroll
            for (int it = 0; it < PT; ++it) {
                int e   = it*256 + tid;
                int row = e / (BK/4);
                int c4  = e % (BK/4);
                const unsigned short* src = A + (size_t)(bm0+row)*K + kt + c4*4;
                ushort4 uv = *(const ushort4*)src;
                As[(c4*4+0)*BMP + row] = bf2f(uv.x);
                As[(c4*4+1)*BMP + row] = bf2f(uv.y);
                As[(c4*4+2)*BMP + row] = bf2f(uv.z);
                As[(c4*4+3)*BMP + row] = bf2f(uv.w);
            }
        } else {
            const float* A = (const float*)Ap;
            constexpr int PT = (BM*BK/4)/256;
#pragma unroll
            for (int it = 0; it < PT; ++it) {
                int e   = it*256 + tid;
                int row = e / (BK/4);
                int c4  = e % (BK/4);
                float4 fv = *(const float4*)(A + (size_t)(bm0+row)*K + kt + c4*4);
                As[(c4*4+0)*BMP + row] = fv.x;
                As[(c4*4+1)*BMP + row] = fv.y;
                As[(c4*4+2)*BMP + row] = fv.z;
                As[(c4*4+3)*BMP + row] = fv.w;
            }
        }
        {
            constexpr int PT = (BN*BK/4)/256;
#pragma unroll
            for (int it = 0; it < PT; ++it) {
                int e   = it*256 + tid;
                int row = e / (BK/4);
                int c4  = e % (BK/4);
                float4 fv = *(const float4*)(Bp + (size_t)(bn0+row)*K + kt + c4*4);
                Bs[(c4*4+0)*BNP + row] = fv.x;
                Bs[(c4*4+1)*BNP + row] = fv.y;
                Bs[(c4*4+2)*BNP + row] = fv.z;
                Bs[(c4*4+3)*BNP + row] = fv.w;
            }
        }
        __syncthreads();
#pragma unroll
        for (int k = 0; k < BK; ++k) {
            float a[TM], b[TN];
#pragma unroll
            for (int i = 0; i < TM/4; ++i) {
                float4 t4 = *(const float4*)&As[k*BMP + ty*TM + i*4];
                a[i*4+0] = t4.x; a[i*4+1] = t4.y; a[i*4+2] = t4.z; a[i*4+3] = t4.w;
            }
#pragma unroll
            for (int j = 0; j < TN/4; ++j) {
                float4 t4 = *(const float4*)&Bs[k*BNP + tx*TN + j*4];
                b[j*4+0] = t4.x; b[j*4+1] = t4.y; b[j*4+2] = t4.z; b[j*4+3] = t4.w;
            }
#pragma unroll
            for (int i = 0; i < TM; ++i)
#pragma unroll
                for (int j = 0; j < TN; ++j)
                    acc[i][j] = fmaf(a[i], b[j], acc[i][j]);
        }
        __syncthreads();
    }

    if constexpr (MODE == 0) {
#pragma unroll
        for (int i = 0; i < TM; ++i) {
            int m = bm0 + ty*TM + i;
#pragma unroll
            for (int j = 0; j < TN/4; ++j) {
                int n = bn0 + tx*TN + j*4;
                float4 bv = *(const float4*)&bias[n];
                float4 o;
                o.x = acc[i][j*4+0] + bv.x;
                o.y = acc[i][j*4+1] + bv.y;
                o.z = acc[i][j*4+2] + bv.z;
                o.w = acc[i][j*4+3] + bv.w;
                *(float4*)&Cout[(size_t)m*ldc + n] = o;
            }
        }
    } else {   // MODE == 1
        float decay = 1.f / (1.f + expf(-wlif[0]));
#pragma unroll
        for (int i = 0; i < TM; ++i) {
            int m = bm0 + ty*TM + i;
#pragma unroll
            for (int j = 0; j < TN; ++j) {
                int n = bn0 + tx*TN + j;
                size_t idx = (size_t)m*H_DIM + n;
                float inp = acc[i][j] + bias[n] + curr_t[idx];
                float vv  = vstate[idx];
                vv = vv + (inp - vv) * decay;
                bool s = (vv - 1.0f) >= 0.0f;
                vstate[idx]  = s ? 0.0f : vv;
                spk_out[idx] = s ? (unsigned short)0x3F80 : (unsigned short)0;
            }
        }
    }
}

// ======== MFMA GEMM for fc2 only (feeds BN; loose tolerance) ========
// C = A @ B^T; A bf16 spikes (exact); B as 2 bf16 planes (h+m of W2).
template<int BM, int BN, int WM, int WN, int MI, int NI>
__global__ __launch_bounds__(256)
void mfma_fc2(const unsigned short* __restrict__ Aptr,
              const unsigned short* __restrict__ Bhi,
              const unsigned short* __restrict__ Bmi,
              int K,
              const float* __restrict__ bias,
              float* __restrict__ Cout, int ldc,
              float* __restrict__ partials)
{
    constexpr int LP  = 40;
    constexpr int APL = BM * LP;
    constexpr int BPL = BN * LP;
    __shared__ alignas(16) unsigned short sA[APL];
    __shared__ alignas(16) unsigned short sB[2 * BPL];

    // XCD-chunked bijective swizzle (nwg % 8 == 0)
    const int nwg = gridDim.x * gridDim.y;
    const int f   = blockIdx.y * gridDim.x + blockIdx.x;
    const int q   = nwg >> 3;
    const int lg  = (f & 7) * q + (f >> 3);
    const int bn0  = (lg % gridDim.x) * BN;
    const int mblk = lg / gridDim.x;
    const int bm0  = mblk * BM;

    const int tid  = threadIdx.x;
    const int lane = tid & 63;
    const int wid  = tid >> 6;
    const int wr   = wid / WN;
    const int wc   = wid % WN;
    const int lr   = lane & 15;
    const int lk   = lane >> 4;

    f32x4 accB[MI][NI], accS[MI][NI];
#pragma unroll
    for (int i = 0; i < MI; ++i)
#pragma unroll
        for (int j = 0; j < NI; ++j) {
            accB[i][j] = (f32x4){0.f, 0.f, 0.f, 0.f};
            accS[i][j] = (f32x4){0.f, 0.f, 0.f, 0.f};
        }

    for (int kt = 0; kt < K; kt += 32) {
#pragma unroll
        for (int p = 0; p < BM / 64; ++p) {
            int e = p * 256 + tid;
            int row = e >> 2, c8 = e & 3;
            int4 v = *(const int4*)(Aptr + (size_t)(bm0 + row) * K + kt + c8 * 8);
            st8x2(&sA[row * LP + c8 * 8], v);
        }
#pragma unroll
        for (int p = 0; p < BN / 64; ++p) {
            int e = p * 256 + tid;
            int row = e >> 2, c8 = e & 3;
            size_t g = (size_t)(bn0 + row) * K + kt + c8 * 8;
            st8x2(&sB[row * LP + c8 * 8],       *(const int4*)(Bhi + g));
            st8x2(&sB[BPL + row * LP + c8 * 8], *(const int4*)(Bmi + g));
        }
        __syncthreads();

        bf16x8 af[MI], b0[NI], b1[NI];
#pragma unroll
        for (int i = 0; i < MI; ++i) {
            int r = wr * MI * 16 + i * 16 + lr;
            af[i] = ld_frag(&sA[r * LP + lk * 8]);
        }
#pragma unroll
        for (int j = 0; j < NI; ++j) {
            int r = wc * NI * 16 + j * 16 + lr;
            b0[j] = ld_frag(&sB[r * LP + lk * 8]);
            b1[j] = ld_frag(&sB[BPL + r * LP + lk * 8]);
        }
#pragma unroll
        for (int i = 0; i < MI; ++i)
#pragma unroll
            for (int j = 0; j < NI; ++j) {
                accB[i][j] = __builtin_amdgcn_mfma_f32_16x16x32_bf16(af[i], b0[j], accB[i][j], 0, 0, 0);
                accS[i][j] = __builtin_amdgcn_mfma_f32_16x16x32_bf16(af[i], b1[j], accS[i][j], 0, 0, 0);
            }
        __syncthreads();
    }

    // C/D frag: col = lane&15, row = (lane>>4)*4 + r  [m89]
    float csum[NI], csq[NI];
#pragma unroll
    for (int j = 0; j < NI; ++j) { csum[j] = 0.f; csq[j] = 0.f; }
#pragma unroll
    for (int i = 0; i < MI; ++i)
#pragma unroll
        for (int j = 0; j < NI; ++j) {
            int col = bn0 + wc * NI * 16 + j * 16 + lr;
            float bv = bias[col];
#pragma unroll
            for (int r = 0; r < 4; ++r) {
                int row = bm0 + wr * MI * 16 + i * 16 + lk * 4 + r;
                float o = (accB[i][j][r] + accS[i][j][r]) + bv;
                Cout[(size_t)row * ldc + col] = o;
                csum[j] += o;
                csq[j]  += o * o;
            }
        }
    __syncthreads();                       // LDS tiles dead; reuse for reduce
    float* redS = (float*)sA;              // WM*4 x BN floats
    float* redQ = (float*)sB;
    const int slot = wr * 4 + lk;
#pragma unroll
    for (int j = 0; j < NI; ++j) {
        int c = wc * NI * 16 + j * 16 + lr;
        redS[slot * BN + c] = csum[j];
        redQ[slot * BN + c] = csq[j];
    }
    __syncthreads();
    if (tid < BN) {
        float s = 0.f, qq = 0.f;
        for (int sl = 0; sl < WM * 4; ++sl) { s += redS[sl * BN + tid]; qq += redQ[sl * BN + tid]; }
        partials[((size_t)mblk * 2 + 0) * O_DIM + bn0 + tid] = s;
        partials[((size_t)mblk * 2 + 1) * O_DIM + bn0 + tid] = qq;
    }
}

__global__ void bn_finalize(const float* __restrict__ partials,
                            const float* __restrict__ gamma,
                            const float* __restrict__ beta,
                            float* __restrict__ scsh, int nmblk)
{
    int o = threadIdx.x;   // 512 threads
    float s = 0.f, q = 0.f;
    for (int mb = 0; mb < nmblk; ++mb) {
        s += partials[((size_t)mb*2 + 0)*O_DIM + o];
        q += partials[((size_t)mb*2 + 1)*O_DIM + o];
    }
    const float invn = 1.f / (float)TBN_DIM;
    float mean = s * invn;
    float var  = q * invn - mean*mean;
    float sc   = gamma[o] * rsqrtf(var + 1e-5f);
    scsh[o]        = sc;
    scsh[O_DIM+o]  = beta[o] - mean*sc;
}

__global__ void bn_apply(float* __restrict__ out, const float* __restrict__ scsh)
{
    const size_t total4 = (size_t)TBN_DIM * O_DIM / 4;
    const float4* sc4 = (const float4*)scsh;
    const float4* sh4 = (const float4*)(scsh + O_DIM);
    size_t stride = (size_t)gridDim.x * blockDim.x;
    for (size_t idx = (size_t)blockIdx.x*blockDim.x + threadIdx.x; idx < total4; idx += stride) {
        float4 v = ((float4*)out)[idx];
        int c4 = (int)(idx & (O_DIM/4 - 1));
        float4 sc = sc4[c4], sh = sh4[c4];
        v.x = v.x*sc.x + sh.x;
        v.y = v.y*sc.y + sh.y;
        v.z = v.z*sc.z + sh.z;
        v.w = v.w*sc.w + sh.w;
        ((float4*)out)[idx] = v;
    }
}

extern "C" void kernel_launch(void* const* d_in, const int* in_sizes, int n_in,
                              void* d_out, int out_size, void* d_ws, size_t ws_size,
                              hipStream_t stream) {
    const float* x     = (const float*)d_in[0];
    const float* W1    = (const float*)d_in[1];
    const float* b1    = (const float*)d_in[2];
    const float* Wrec  = (const float*)d_in[3];
    const float* brec  = (const float*)d_in[4];
    const float* wlif  = (const float*)d_in[5];
    const float* W2    = (const float*)d_in[6];
    const float* b2    = (const float*)d_in[7];
    const float* gamma = (const float*)d_in[8];
    const float* beta  = (const float*)d_in[9];
    float* out = (float*)d_out;

    // ws layout (~414.2 MB, within round-1's proven footprint)
    char* w = (char*)d_ws;
    float*          curr   = (float*)w;                            // 256 MB
    unsigned short* spk    = (unsigned short*)(w + 268435456);     // 128 MB, slots 0..31
    float*          vstate = (float*)(w + 402653184);              // 8 MB
    unsigned short* w2p    = (unsigned short*)(w + 411041792);     // W2 3 planes, 3 MB
    float* partials = curr;                 // overlay: curr dead after scan
    float* scsh     = curr + 512 * 2 * O_DIM;

    const int W2N = O_DIM * H_DIM;          // 524288

    // fc1: curr = x @ W1^T + b1   (round-1 fp32 engine, verbatim)
    gemm_fused<0,128,128,16,8,8,false>
        <<<dim3(H_DIM/128, TBN_DIM/128), 256, 0, stream>>>(
            x, W1, C_DIM, H_DIM, b1,
            nullptr, nullptr, nullptr, nullptr, curr);

    // t=0 (bit-exact elementwise replacement of GEMM-of-zeros; inits vstate)
    step0_kernel<<<dim3(512), 256, 0, stream>>>(curr, brec, wlif, vstate, spk);

    // recurrent scan t=1..31 (round-1 fp32 engine, verbatim)
    for (int t = 1; t < T_STEPS; ++t) {
        gemm_fused<1,64,128,16,4,8,true>
            <<<dim3(H_DIM/128, BNROWS/64), 256, 0, stream>>>(
                spk + (size_t)(t-1) * BNROWS * H_DIM, Wrec, H_DIM, H_DIM, brec,
                curr + (size_t)t * BNROWS * H_DIM, vstate,
                spk + (size_t)t * BNROWS * H_DIM, wlif, nullptr);
    }

    // fc2 (BN-only consumer): 2-plane bf16 MFMA + fused BN partials
    split3_w<<<dim3(256), 256, 0, stream>>>(W2, w2p, w2p + W2N, w2p + 2 * W2N, W2N / 4);
    mfma_fc2<128, 128, 2, 2, 4, 4>
        <<<dim3(O_DIM/128, TBN_DIM/128), 256, 0, stream>>>(
            spk, w2p, w2p + W2N, H_DIM, b2, out, O_DIM, partials);

    bn_finalize<<<1, O_DIM, 0, stream>>>(partials, gamma, beta, scsh, TBN_DIM/128);
    bn_apply<<<2048, 256, 0, stream>>>(out, scsh);
}

// Round 6
// 3832.600 us; speedup vs baseline: 1.2131x; 1.1049x over previous
//
#include <hip/hip_runtime.h>
#include <cstdint>
#include <cstddef>

#define T_STEPS 32
#define BNROWS  2048     // B*N
#define C_DIM   512
#define H_DIM   1024
#define O_DIM   512
#define TBN_DIM 65536    // T_STEPS*BNROWS

typedef __attribute__((ext_vector_type(8))) short bf16x8;
typedef __attribute__((ext_vector_type(4))) float f32x4;

__device__ __forceinline__ float bf2f(unsigned short u){
    return __uint_as_float(((unsigned int)u) << 16);
}

// Exact 3-way truncation split: x == h + m + l exactly.
__device__ __forceinline__ void split3(float x, unsigned short& h,
                                       unsigned short& m, unsigned short& l){
    unsigned u = __float_as_uint(x);
    h = (unsigned short)(u >> 16);
    float r1 = x - __uint_as_float(u & 0xFFFF0000u);
    unsigned u1 = __float_as_uint(r1);
    m = (unsigned short)(u1 >> 16);
    float r2 = r1 - __uint_as_float(u1 & 0xFFFF0000u);
    l = (unsigned short)(__float_as_uint(r2) >> 16);
}

__global__ void split3_w(const float* __restrict__ src,
                         unsigned short* __restrict__ hi,
                         unsigned short* __restrict__ mi,
                         unsigned short* __restrict__ lo, int n4)
{
    int i = blockIdx.x * blockDim.x + threadIdx.x;
    int stride = gridDim.x * blockDim.x;
    for (; i < n4; i += stride) {
        float4 v = ((const float4*)src)[i];
        ushort4 h, m, l;
        split3(v.x, h.x, m.x, l.x); split3(v.y, h.y, m.y, l.y);
        split3(v.z, h.z, m.z, l.z); split3(v.w, h.w, m.w, l.w);
        ((ushort4*)hi)[i] = h;
        ((ushort4*)mi)[i] = m;
        ((ushort4*)lo)[i] = l;
    }
}

// 8-byte-granular LDS helpers for the MFMA kernel (LP=40 ushort rows = 80 B)
__device__ __forceinline__ void st8x2(unsigned short* p, int4 v){
    ((int2*)p)[0] = make_int2(v.x, v.y);
    ((int2*)p)[1] = make_int2(v.z, v.w);
}
__device__ __forceinline__ bf16x8 ld_frag(const unsigned short* p){
    union { bf16x8 v; ushort4 u[2]; } t;
    t.u[0] = *(const ushort4*)(p);
    t.u[1] = *(const ushort4*)(p + 4);
    return t.v;
}

// t=0 PLIF step (prev spikes all zero). Bit-exact to the GEMM-of-zeros path.
__global__ void step0_kernel(const float* __restrict__ curr0,
                             const float* __restrict__ brec,
                             const float* __restrict__ wlif,
                             float* __restrict__ vstate,
                             unsigned short* __restrict__ spk0)
{
    const float decay = 1.f / (1.f + expf(-wlif[0]));
    int i = blockIdx.x * blockDim.x + threadIdx.x;
    int stride = gridDim.x * blockDim.x;
    const int n4 = BNROWS * H_DIM / 4;
    for (; i < n4; i += stride) {
        float4 c = ((const float4*)curr0)[i];
        int col4 = (i * 4) & (H_DIM - 1);
        float4 b = *(const float4*)&brec[col4];
        float v0 = __fmul_rn(__fadd_rn(b.x, c.x), decay);
        float v1 = __fmul_rn(__fadd_rn(b.y, c.y), decay);
        float v2 = __fmul_rn(__fadd_rn(b.z, c.z), decay);
        float v3 = __fmul_rn(__fadd_rn(b.w, c.w), decay);
        bool s0 = (v0 - 1.0f) >= 0.0f, s1 = (v1 - 1.0f) >= 0.0f;
        bool s2 = (v2 - 1.0f) >= 0.0f, s3 = (v3 - 1.0f) >= 0.0f;
        float4 vo; vo.x = s0 ? 0.f : v0; vo.y = s1 ? 0.f : v1;
        vo.z = s2 ? 0.f : v2; vo.w = s3 ? 0.f : v3;
        ushort4 sp;
        sp.x = s0 ? 0x3F80 : 0; sp.y = s1 ? 0x3F80 : 0;
        sp.z = s2 ? 0x3F80 : 0; sp.w = s3 ? 0x3F80 : 0;
        ((float4*)vstate)[i] = vo;
        ((ushort4*)spk0)[i]  = sp;
    }
}

// ======== fp32 VALU GEMM, double-buffered staging. Per-output arithmetic is
// bit-identical to the round-1/5 passing kernel: same LDS slot values, same
// ascending-k fmaf chain, same epilogue expressions. Only the staging schedule
// (global->reg->LDS, one barrier/tile) and tile->thread mapping changed.
// MODE 0: fc1  -> Cout = acc + bias
// MODE 1: rec  -> PLIF update epilogue (reads curr_t, v; writes v, spikes)
template<int MODE, int BM, int BN, int BK, int TM, int TN, bool ABF16>
__global__ __launch_bounds__(256)
void gemm_fused(const void* __restrict__ Ap,
                const float* __restrict__ Bp,
                int K, int ldc,
                const float* __restrict__ bias,
                const float* __restrict__ curr_t,
                float* __restrict__ vstate,
                unsigned short* __restrict__ spk_out,
                const float* __restrict__ wlif,
                float* __restrict__ Cout)
{
    constexpr int BMP  = BM + 4;
    constexpr int BNP  = BN + 4;
    constexpr int TILE = BK * BMP + BK * BNP;
    __shared__ float smem[2 * TILE];

    const int tid = threadIdx.x;
    constexpr int TXN = BN / TN;
    const int tx = tid % TXN;
    const int ty = tid / TXN;
    const int bm0 = blockIdx.y * BM;
    const int bn0 = blockIdx.x * BN;

    constexpr int CPR = BK / 4;              // float4 chunks per row
    constexpr int PTA = (BM * BK / 4) / 256; // per-thread A chunks
    constexpr int PTB = (BN * BK / 4) / 256;

    float4  rAf[PTA];
    ushort4 rAh[PTA];
    float4  rB[PTB];

    auto load_tiles = [&](int kt) {
#pragma unroll
        for (int it = 0; it < PTA; ++it) {
            int e = it * 256 + tid;
            int row = e / CPR, c4 = e % CPR;
            if constexpr (ABF16)
                rAh[it] = *(const ushort4*)((const unsigned short*)Ap + (size_t)(bm0 + row) * K + kt + c4 * 4);
            else
                rAf[it] = *(const float4*)((const float*)Ap + (size_t)(bm0 + row) * K + kt + c4 * 4);
        }
#pragma unroll
        for (int it = 0; it < PTB; ++it) {
            int e = it * 256 + tid;
            int row = e / CPR, c4 = e % CPR;
            rB[it] = *(const float4*)(Bp + (size_t)(bn0 + row) * K + kt + c4 * 4);
        }
    };
    auto store_tiles = [&](float* buf) {
        float* As = buf;
        float* Bs = buf + BK * BMP;
#pragma unroll
        for (int it = 0; it < PTA; ++it) {
            int e = it * 256 + tid;
            int row = e / CPR, c4 = e % CPR;
            if constexpr (ABF16) {
                As[(c4*4+0)*BMP + row] = bf2f(rAh[it].x);
                As[(c4*4+1)*BMP + row] = bf2f(rAh[it].y);
                As[(c4*4+2)*BMP + row] = bf2f(rAh[it].z);
                As[(c4*4+3)*BMP + row] = bf2f(rAh[it].w);
            } else {
                As[(c4*4+0)*BMP + row] = rAf[it].x;
                As[(c4*4+1)*BMP + row] = rAf[it].y;
                As[(c4*4+2)*BMP + row] = rAf[it].z;
                As[(c4*4+3)*BMP + row] = rAf[it].w;
            }
        }
#pragma unroll
        for (int it = 0; it < PTB; ++it) {
            int e = it * 256 + tid;
            int row = e / CPR, c4 = e % CPR;
            Bs[(c4*4+0)*BNP + row] = rB[it].x;
            Bs[(c4*4+1)*BNP + row] = rB[it].y;
            Bs[(c4*4+2)*BNP + row] = rB[it].z;
            Bs[(c4*4+3)*BNP + row] = rB[it].w;
        }
    };

    float acc[TM][TN];
#pragma unroll
    for (int i = 0; i < TM; ++i)
#pragma unroll
        for (int j = 0; j < TN; ++j) acc[i][j] = 0.f;

    load_tiles(0);
    store_tiles(smem);
    __syncthreads();

    int cur = 0;
    for (int kt = 0; kt < K; kt += BK) {
        const bool more = (kt + BK) < K;
        if (more) load_tiles(kt + BK);
        const float* As = smem + cur * TILE;
        const float* Bs = As + BK * BMP;
#pragma unroll
        for (int k = 0; k < BK; ++k) {
            float a[TM], b[TN];
#pragma unroll
            for (int i = 0; i < TM/4; ++i) {
                float4 t4 = *(const float4*)&As[k*BMP + ty*TM + i*4];
                a[i*4+0] = t4.x; a[i*4+1] = t4.y; a[i*4+2] = t4.z; a[i*4+3] = t4.w;
            }
#pragma unroll
            for (int j = 0; j < TN/4; ++j) {
                float4 t4 = *(const float4*)&Bs[k*BNP + tx*TN + j*4];
                b[j*4+0] = t4.x; b[j*4+1] = t4.y; b[j*4+2] = t4.z; b[j*4+3] = t4.w;
            }
#pragma unroll
            for (int i = 0; i < TM; ++i)
#pragma unroll
                for (int j = 0; j < TN; ++j)
                    acc[i][j] = fmaf(a[i], b[j], acc[i][j]);
        }
        if (more) store_tiles(smem + (cur ^ 1) * TILE);
        __syncthreads();
        cur ^= 1;
    }

    if constexpr (MODE == 0) {
#pragma unroll
        for (int i = 0; i < TM; ++i) {
            int m = bm0 + ty*TM + i;
#pragma unroll
            for (int j = 0; j < TN/4; ++j) {
                int n = bn0 + tx*TN + j*4;
                float4 bv = *(const float4*)&bias[n];
                float4 o;
                o.x = acc[i][j*4+0] + bv.x;
                o.y = acc[i][j*4+1] + bv.y;
                o.z = acc[i][j*4+2] + bv.z;
                o.w = acc[i][j*4+3] + bv.w;
                *(float4*)&Cout[(size_t)m*ldc + n] = o;
            }
        }
    } else {   // MODE == 1
        float decay = 1.f / (1.f + expf(-wlif[0]));
#pragma unroll
        for (int i = 0; i < TM; ++i) {
            int m = bm0 + ty*TM + i;
#pragma unroll
            for (int j = 0; j < TN; ++j) {
                int n = bn0 + tx*TN + j;
                size_t idx = (size_t)m*H_DIM + n;
                float inp = acc[i][j] + bias[n] + curr_t[idx];
                float vv  = vstate[idx];
                vv = vv + (inp - vv) * decay;
                bool s = (vv - 1.0f) >= 0.0f;
                vstate[idx]  = s ? 0.0f : vv;
                spk_out[idx] = s ? (unsigned short)0x3F80 : (unsigned short)0;
            }
        }
    }
}

// ======== MFMA GEMM for fc2 only (feeds BN; loose tolerance) ========
template<int BM, int BN, int WM, int WN, int MI, int NI>
__global__ __launch_bounds__(256)
void mfma_fc2(const unsigned short* __restrict__ Aptr,
              const unsigned short* __restrict__ Bhi,
              const unsigned short* __restrict__ Bmi,
              int K,
              const float* __restrict__ bias,
              float* __restrict__ Cout, int ldc,
              float* __restrict__ partials)
{
    constexpr int LP  = 40;
    constexpr int APL = BM * LP;
    constexpr int BPL = BN * LP;
    __shared__ alignas(16) unsigned short sA[APL];
    __shared__ alignas(16) unsigned short sB[2 * BPL];

    const int nwg = gridDim.x * gridDim.y;
    const int f   = blockIdx.y * gridDim.x + blockIdx.x;
    const int q   = nwg >> 3;
    const int lg  = (f & 7) * q + (f >> 3);
    const int bn0  = (lg % gridDim.x) * BN;
    const int mblk = lg / gridDim.x;
    const int bm0  = mblk * BM;

    const int tid  = threadIdx.x;
    const int lane = tid & 63;
    const int wid  = tid >> 6;
    const int wr   = wid / WN;
    const int wc   = wid % WN;
    const int lr   = lane & 15;
    const int lk   = lane >> 4;

    f32x4 accB[MI][NI], accS[MI][NI];
#pragma unroll
    for (int i = 0; i < MI; ++i)
#pragma unroll
        for (int j = 0; j < NI; ++j) {
            accB[i][j] = (f32x4){0.f, 0.f, 0.f, 0.f};
            accS[i][j] = (f32x4){0.f, 0.f, 0.f, 0.f};
        }

    for (int kt = 0; kt < K; kt += 32) {
#pragma unroll
        for (int p = 0; p < BM / 64; ++p) {
            int e = p * 256 + tid;
            int row = e >> 2, c8 = e & 3;
            int4 v = *(const int4*)(Aptr + (size_t)(bm0 + row) * K + kt + c8 * 8);
            st8x2(&sA[row * LP + c8 * 8], v);
        }
#pragma unroll
        for (int p = 0; p < BN / 64; ++p) {
            int e = p * 256 + tid;
            int row = e >> 2, c8 = e & 3;
            size_t g = (size_t)(bn0 + row) * K + kt + c8 * 8;
            st8x2(&sB[row * LP + c8 * 8],       *(const int4*)(Bhi + g));
            st8x2(&sB[BPL + row * LP + c8 * 8], *(const int4*)(Bmi + g));
        }
        __syncthreads();

        bf16x8 af[MI], b0[NI], b1[NI];
#pragma unroll
        for (int i = 0; i < MI; ++i) {
            int r = wr * MI * 16 + i * 16 + lr;
            af[i] = ld_frag(&sA[r * LP + lk * 8]);
        }
#pragma unroll
        for (int j = 0; j < NI; ++j) {
            int r = wc * NI * 16 + j * 16 + lr;
            b0[j] = ld_frag(&sB[r * LP + lk * 8]);
            b1[j] = ld_frag(&sB[BPL + r * LP + lk * 8]);
        }
#pragma unroll
        for (int i = 0; i < MI; ++i)
#pragma unroll
            for (int j = 0; j < NI; ++j) {
                accB[i][j] = __builtin_amdgcn_mfma_f32_16x16x32_bf16(af[i], b0[j], accB[i][j], 0, 0, 0);
                accS[i][j] = __builtin_amdgcn_mfma_f32_16x16x32_bf16(af[i], b1[j], accS[i][j], 0, 0, 0);
            }
        __syncthreads();
    }

    float csum[NI], csq[NI];
#pragma unroll
    for (int j = 0; j < NI; ++j) { csum[j] = 0.f; csq[j] = 0.f; }
#pragma unroll
    for (int i = 0; i < MI; ++i)
#pragma unroll
        for (int j = 0; j < NI; ++j) {
            int col = bn0 + wc * NI * 16 + j * 16 + lr;
            float bv = bias[col];
#pragma unroll
            for (int r = 0; r < 4; ++r) {
                int row = bm0 + wr * MI * 16 + i * 16 + lk * 4 + r;
                float o = (accB[i][j][r] + accS[i][j][r]) + bv;
                Cout[(size_t)row * ldc + col] = o;
                csum[j] += o;
                csq[j]  += o * o;
            }
        }
    __syncthreads();
    float* redS = (float*)sA;
    float* redQ = (float*)sB;
    const int slot = wr * 4 + lk;
#pragma unroll
    for (int j = 0; j < NI; ++j) {
        int c = wc * NI * 16 + j * 16 + lr;
        redS[slot * BN + c] = csum[j];
        redQ[slot * BN + c] = csq[j];
    }
    __syncthreads();
    if (tid < BN) {
        float s = 0.f, qq = 0.f;
        for (int sl = 0; sl < WM * 4; ++sl) { s += redS[sl * BN + tid]; qq += redQ[sl * BN + tid]; }
        partials[((size_t)mblk * 2 + 0) * O_DIM + bn0 + tid] = s;
        partials[((size_t)mblk * 2 + 1) * O_DIM + bn0 + tid] = qq;
    }
}

__global__ void bn_finalize(const float* __restrict__ partials,
                            const float* __restrict__ gamma,
                            const float* __restrict__ beta,
                            float* __restrict__ scsh, int nmblk)
{
    int o = threadIdx.x;   // 512 threads
    float s = 0.f, q = 0.f;
    for (int mb = 0; mb < nmblk; ++mb) {
        s += partials[((size_t)mb*2 + 0)*O_DIM + o];
        q += partials[((size_t)mb*2 + 1)*O_DIM + o];
    }
    const float invn = 1.f / (float)TBN_DIM;
    float mean = s * invn;
    float var  = q * invn - mean*mean;
    float sc   = gamma[o] * rsqrtf(var + 1e-5f);
    scsh[o]        = sc;
    scsh[O_DIM+o]  = beta[o] - mean*sc;
}

__global__ void bn_apply(float* __restrict__ out, const float* __restrict__ scsh)
{
    const size_t total4 = (size_t)TBN_DIM * O_DIM / 4;
    const float4* sc4 = (const float4*)scsh;
    const float4* sh4 = (const float4*)(scsh + O_DIM);
    size_t stride = (size_t)gridDim.x * blockDim.x;
    for (size_t idx = (size_t)blockIdx.x*blockDim.x + threadIdx.x; idx < total4; idx += stride) {
        float4 v = ((float4*)out)[idx];
        int c4 = (int)(idx & (O_DIM/4 - 1));
        float4 sc = sc4[c4], sh = sh4[c4];
        v.x = v.x*sc.x + sh.x;
        v.y = v.y*sc.y + sh.y;
        v.z = v.z*sc.z + sh.z;
        v.w = v.w*sc.w + sh.w;
        ((float4*)out)[idx] = v;
    }
}

extern "C" void kernel_launch(void* const* d_in, const int* in_sizes, int n_in,
                              void* d_out, int out_size, void* d_ws, size_t ws_size,
                              hipStream_t stream) {
    const float* x     = (const float*)d_in[0];
    const float* W1    = (const float*)d_in[1];
    const float* b1    = (const float*)d_in[2];
    const float* Wrec  = (const float*)d_in[3];
    const float* brec  = (const float*)d_in[4];
    const float* wlif  = (const float*)d_in[5];
    const float* W2    = (const float*)d_in[6];
    const float* b2    = (const float*)d_in[7];
    const float* gamma = (const float*)d_in[8];
    const float* beta  = (const float*)d_in[9];
    float* out = (float*)d_out;

    // ws layout (~414.2 MB)
    char* w = (char*)d_ws;
    float*          curr   = (float*)w;                            // 256 MB
    unsigned short* spk    = (unsigned short*)(w + 268435456);     // 128 MB, slots 0..31
    float*          vstate = (float*)(w + 402653184);              // 8 MB
    unsigned short* w2p    = (unsigned short*)(w + 411041792);     // W2 3 planes, 3 MB
    float* partials = curr;                 // overlay: curr dead after scan
    float* scsh     = curr + 512 * 2 * O_DIM;

    const int W2N = O_DIM * H_DIM;          // 524288

    // fc1: curr = x @ W1^T + b1   (fp32 engine, dbuf; bit-exact chain)
    gemm_fused<0,128,128,16,8,8,false>
        <<<dim3(H_DIM/128, TBN_DIM/128), 256, 0, stream>>>(
            x, W1, C_DIM, H_DIM, b1,
            nullptr, nullptr, nullptr, nullptr, curr);

    // t=0 (bit-exact elementwise replacement of GEMM-of-zeros; inits vstate)
    step0_kernel<<<dim3(512), 256, 0, stream>>>(curr, brec, wlif, vstate, spk);

    // recurrent scan t=1..31 (fp32 engine, dbuf, 64x64 tile -> 512 blocks)
    for (int t = 1; t < T_STEPS; ++t) {
        gemm_fused<1,64,64,16,4,4,true>
            <<<dim3(H_DIM/64, BNROWS/64), 256, 0, stream>>>(
                spk + (size_t)(t-1) * BNROWS * H_DIM, Wrec, H_DIM, H_DIM, brec,
                curr + (size_t)t * BNROWS * H_DIM, vstate,
                spk + (size_t)t * BNROWS * H_DIM, wlif, nullptr);
    }

    // fc2 (BN-only consumer): 2-plane bf16 MFMA + fused BN partials
    split3_w<<<dim3(256), 256, 0, stream>>>(W2, w2p, w2p + W2N, w2p + 2 * W2N, W2N / 4);
    mfma_fc2<128, 128, 2, 2, 4, 4>
        <<<dim3(O_DIM/128, TBN_DIM/128), 256, 0, stream>>>(
            spk, w2p, w2p + W2N, H_DIM, b2, out, O_DIM, partials);

    bn_finalize<<<1, O_DIM, 0, stream>>>(partials, gamma, beta, scsh, TBN_DIM/128);
    bn_apply<<<2048, 256, 0, stream>>>(out, scsh);
}